// Round 1
// baseline (14.966 us; speedup 1.0000x reference)
//
#include <hip/hip_runtime.h>
#include <math.h>

// PromptEncoder (SAM-style): B=points.rows/… derived from in_sizes.
// out[b,d] = ( sum_n trig_d(f(points[b,n])) + cnt_{-1}*nap[d] + cnt_{1}*pe0[d]
//              + cnt_{0}*pe1[d] + 0.5*(trig_d(c0)+pe2[d] + trig_d(c1)+pe3[d]) ) / (N+1)
// trig_d = sin for d<128, cos for d>=128; f(p) = ((p+0.5)/512 - 1) @ gauss  (revolutions)

#define N_PTS 128
#define NFEAT 128   // D/2

__device__ __forceinline__ float sin2pi(float t) { return __builtin_amdgcn_sinf(t); }
__device__ __forceinline__ float cos2pi(float t) { return __builtin_amdgcn_cosf(t); }
__device__ __forceinline__ float fract_(float t) { return __builtin_amdgcn_fractf(t); }

__global__ __launch_bounds__(128)
void prompt_encoder_kernel(const float* __restrict__ points,  // [B,N,2]
                           const int*   __restrict__ labels,  // [B,N]
                           const float* __restrict__ boxes,   // [B,4]
                           const float* __restrict__ gauss,   // [2,128]
                           const float* __restrict__ pe0,
                           const float* __restrict__ pe1,
                           const float* __restrict__ pe2,
                           const float* __restrict__ pe3,
                           const float* __restrict__ nap,
                           float* __restrict__ out)           // [B,256]
{
    const int b = blockIdx.x;
    const int j = threadIdx.x;  // feature index 0..127

    __shared__ float sc[2 * N_PTS];  // normalized c-values, interleaved (cx,cy)
    __shared__ int   scnt[3];        // counts of labels -1, 0, 1

    // Stage points -> c = (p+0.5)/512 - 1 into LDS; zero counters.
    {
        float2 p = ((const float2*)(points + (size_t)b * N_PTS * 2))[j];
        sc[2 * j]     = (p.x + 0.5f) * (1.0f / 512.0f) - 1.0f;
        sc[2 * j + 1] = (p.y + 0.5f) * (1.0f / 512.0f) - 1.0f;
        if (j < 3) scnt[j] = 0;
    }
    __syncthreads();
    {
        int lab = labels[(size_t)b * N_PTS + j];  // in {-1,0,1}
        atomicAdd(&scnt[lab + 1], 1);
    }

    const float g0 = gauss[j];
    const float g1 = gauss[NFEAT + j];

    __syncthreads();

    float ssum = 0.0f, csum = 0.0f;
    #pragma unroll 8
    for (int n = 0; n < N_PTS; ++n) {
        float cx = sc[2 * n];
        float cy = sc[2 * n + 1];
        float t  = fract_(cx * g0 + cy * g1);  // revolutions, reduced to [0,1)
        ssum += sin2pi(t);
        csum += cos2pi(t);
    }

    // Label-delta contribution: sum over n of selected PE vector.
    float cm1 = (float)scnt[0];  // lab == -1 -> nap
    float c0  = (float)scnt[1];  // lab ==  0 -> pe1
    float cp1 = (float)scnt[2];  // lab ==  1 -> pe0

    const int ds = j;          // sin output channel
    const int dc = j + NFEAT;  // cos output channel
    float dels = cm1 * nap[ds] + cp1 * pe0[ds] + c0 * pe1[ds];
    float delc = cm1 * nap[dc] + cp1 * pe0[dc] + c0 * pe1[dc];

    // Box: two corners, each PE-encoded + pe2/pe3, then averaged.
    float4 bx  = ((const float4*)boxes)[b];
    float c0x = (bx.x + 0.5f) * (1.0f / 512.0f) - 1.0f;
    float c0y = (bx.y + 0.5f) * (1.0f / 512.0f) - 1.0f;
    float c1x = (bx.z + 0.5f) * (1.0f / 512.0f) - 1.0f;
    float c1y = (bx.w + 0.5f) * (1.0f / 512.0f) - 1.0f;
    float t0 = fract_(c0x * g0 + c0y * g1);
    float t1 = fract_(c1x * g0 + c1y * g1);
    float boxs = 0.5f * ((sin2pi(t0) + pe2[ds]) + (sin2pi(t1) + pe3[ds]));
    float boxc = 0.5f * ((cos2pi(t0) + pe2[dc]) + (cos2pi(t1) + pe3[dc]));

    const float inv_np1 = 1.0f / (float)(N_PTS + 1);
    out[(size_t)b * 256 + ds] = (ssum + dels + boxs) * inv_np1;
    out[(size_t)b * 256 + dc] = (csum + delc + boxc) * inv_np1;
}

extern "C" void kernel_launch(void* const* d_in, const int* in_sizes, int n_in,
                              void* d_out, int out_size, void* d_ws, size_t ws_size,
                              hipStream_t stream) {
    const float* points = (const float*)d_in[0];
    const int*   labels = (const int*)d_in[1];
    const float* boxes  = (const float*)d_in[2];
    const float* gauss  = (const float*)d_in[3];
    const float* pe0    = (const float*)d_in[4];
    const float* pe1    = (const float*)d_in[5];
    const float* pe2    = (const float*)d_in[6];
    const float* pe3    = (const float*)d_in[7];
    const float* nap    = (const float*)d_in[8];
    float* out = (float*)d_out;

    const int B = in_sizes[2] / 4;  // boxes is [B,4]

    prompt_encoder_kernel<<<B, 128, 0, stream>>>(points, labels, boxes, gauss,
                                                 pe0, pe1, pe2, pe3, nap, out);
}

// Round 2
// 14.511 us; speedup vs baseline: 1.0313x; 1.0313x over previous
//
#include <hip/hip_runtime.h>
#include <math.h>

// PromptEncoder (SAM-style), B=2048, N=128 points, D=256.
// out[b,d] = ( sum_n trig_d(f(points[b,n])) + cnt_{-1}*nap[d] + cnt_{1}*pe0[d]
//              + cnt_{0}*pe1[d] + 0.5*(trig_d(c0)+pe2[d] + trig_d(c1)+pe3[d]) ) / (N+1)
// trig_d = sin for d<128, cos for d>=128; f(p) = ((p+0.5)/512 - 1) @ gauss (revolutions)

#define N_PTS 128
#define NFEAT 128   // D/2

__device__ __forceinline__ float sin2pi(float t) { return __builtin_amdgcn_sinf(t); }
__device__ __forceinline__ float cos2pi(float t) { return __builtin_amdgcn_cosf(t); }
__device__ __forceinline__ float fract_(float t) { return __builtin_amdgcn_fractf(t); }

__global__ __launch_bounds__(256)
void prompt_encoder_kernel(const float* __restrict__ points,  // [B,N,2]
                           const int*   __restrict__ labels,  // [B,N]
                           const float* __restrict__ boxes,   // [B,4]
                           const float* __restrict__ gauss,   // [2,128]
                           const float* __restrict__ pe0,
                           const float* __restrict__ pe1,
                           const float* __restrict__ pe2,
                           const float* __restrict__ pe3,
                           const float* __restrict__ nap,
                           float* __restrict__ out)           // [B,256]
{
    const int b   = blockIdx.x;
    const int tid = threadIdx.x;     // 0..255
    const int j   = tid & (NFEAT - 1);
    const int h   = tid >> 7;        // which half of the point range

    __shared__ float2 sc[N_PTS];          // normalized c-values
    __shared__ float  psin[2 * NFEAT];    // partial sin sums [h][j]
    __shared__ float  pcos[2 * NFEAT];    // partial cos sums [h][j]
    __shared__ int    scnt[4];            // counts of labels -1,0,1

    if (tid < 4) scnt[tid] = 0;
    if (tid < N_PTS) {
        float2 p = ((const float2*)(points + (size_t)b * N_PTS * 2))[tid];
        sc[tid] = make_float2((p.x + 0.5f) * (1.0f / 512.0f) - 1.0f,
                              (p.y + 0.5f) * (1.0f / 512.0f) - 1.0f);
    }
    __syncthreads();

    if (tid < N_PTS) {
        int lab = labels[(size_t)b * N_PTS + tid];  // {-1,0,1}
        atomicAdd(&scnt[lab + 1], 1);
    }

    const float g0 = gauss[j];
    const float g1 = gauss[NFEAT + j];

    float ss = 0.0f, cs = 0.0f;
    const int n0 = h * (N_PTS / 2);
    #pragma unroll 8
    for (int n = 0; n < N_PTS / 2; ++n) {
        float2 c = sc[n0 + n];
        float  t = fract_(fmaf(c.x, g0, c.y * g1));
        ss += sin2pi(t);
        cs += cos2pi(t);
    }
    psin[tid] = ss;
    pcos[tid] = cs;
    __syncthreads();   // covers partials AND label atomics

    // Epilogue: thread tid owns output channel d = tid.
    const int d  = tid;
    const int jj = d & (NFEAT - 1);
    float sum = (d < NFEAT) ? (psin[jj] + psin[NFEAT + jj])
                            : (pcos[jj] + pcos[NFEAT + jj]);

    float cm1 = (float)scnt[0];  // lab == -1 -> nap
    float c0n = (float)scnt[1];  // lab ==  0 -> pe1
    float cp1 = (float)scnt[2];  // lab ==  1 -> pe0
    float delv = cm1 * nap[d] + cp1 * pe0[d] + c0n * pe1[d];

    float gg0 = gauss[jj];
    float gg1 = gauss[NFEAT + jj];
    float4 bx = ((const float4*)boxes)[b];
    float t0 = fract_(fmaf((bx.x + 0.5f) * (1.0f / 512.0f) - 1.0f, gg0,
                           ((bx.y + 0.5f) * (1.0f / 512.0f) - 1.0f) * gg1));
    float t1 = fract_(fmaf((bx.z + 0.5f) * (1.0f / 512.0f) - 1.0f, gg0,
                           ((bx.w + 0.5f) * (1.0f / 512.0f) - 1.0f) * gg1));
    float tr0, tr1;
    if (d < NFEAT) { tr0 = sin2pi(t0); tr1 = sin2pi(t1); }  // wave-uniform branch
    else           { tr0 = cos2pi(t0); tr1 = cos2pi(t1); }
    float box = 0.5f * ((tr0 + pe2[d]) + (tr1 + pe3[d]));

    out[(size_t)b * 256 + d] = (sum + delv + box) * (1.0f / (float)(N_PTS + 1));
}

extern "C" void kernel_launch(void* const* d_in, const int* in_sizes, int n_in,
                              void* d_out, int out_size, void* d_ws, size_t ws_size,
                              hipStream_t stream) {
    const float* points = (const float*)d_in[0];
    const int*   labels = (const int*)d_in[1];
    const float* boxes  = (const float*)d_in[2];
    const float* gauss  = (const float*)d_in[3];
    const float* pe0    = (const float*)d_in[4];
    const float* pe1    = (const float*)d_in[5];
    const float* pe2    = (const float*)d_in[6];
    const float* pe3    = (const float*)d_in[7];
    const float* nap    = (const float*)d_in[8];
    float* out = (float*)d_out;

    const int B = in_sizes[2] / 4;  // boxes is [B,4]

    prompt_encoder_kernel<<<B, 256, 0, stream>>>(points, labels, boxes, gauss,
                                                 pe0, pe1, pe2, pe3, nap, out);
}